// Round 6
// baseline (407.662 us; speedup 1.0000x reference)
//
#include <hip/hip_runtime.h>
#include <hip/hip_bf16.h>

// B=4, S=2048, D=1024.  M = B*S = 8192.
// Workspace layout (bytes):
//   [0,         33554432)  : E bf16 (4*2048*2048) = exp(scores)
//     overlay (dead before attn runs):
//     [0,         16777216) : Xb  bf16 (8192*1024)
//     [16777216,  23068672) : Wt  bf16 (3072*1024)
//   [50331648,  50364416)  : rowsum fp32 (8192)   (zeroed by setup)
//   [50364416,  50364672)  : cnt int32 (64)       (zeroed by setup)
//   [67108864,  83886080)  : Q bf16 (8192*1024)
//   [83886080, 100663296)  : K bf16 (8192*1024)
//   [100663296,117440512)  : Vt bf16 (4*1024*2048) -- written DIRECTLY by qkv
//
// Pipeline (3 launches):
//   setup : cast X->bf16, transpose W->Wt bf16, zero rowsum+cnt
//   qkv   : [8192x1024] x Wt^T -> Q, K row-major; V written directly as Vt
//   attn  : ONE dispatch, 1056 blocks.
//           blocks [0,544):  qk tiles E=exp(QK^T/32) + rowsum atomics;
//                            heavy rows (qi=15) first; release-publish
//                            cnt[b][qi] when a tile finishes.
//           blocks [544,1056): pv tiles; acquire-spin until cnt[b][qi]==qi+1
//                            (row's E + rowsum complete), then
//                            out = (E x V)/rowsum.
//           Deadlock-free by capacity: __launch_bounds__(256,3) forces
//           >=3 blocks/CU resident (768 slots) > 512 pv blocks, so qk
//           blocks always have slots -> unconditional progress.
//           Spin is bounded (~0.1s) so a logic bug fails visibly, not hangs.
//
// R5 post-mortem: qk/pv phases are latency/tail-bound (two serialized
// under-occupied dispatches); this round overlaps them via ready flags.

typedef __attribute__((ext_vector_type(8))) short short8;
typedef __attribute__((ext_vector_type(4))) short s16x4;
typedef __attribute__((ext_vector_type(4))) float f32x4;

__device__ __forceinline__ short f2bf(float f) {
  __hip_bfloat16 h = __float2bfloat16(f);
  return *reinterpret_cast<short*>(&h);
}

__device__ __forceinline__ void gll16(const void* g, void* l) {
  __builtin_amdgcn_global_load_lds((const __attribute__((address_space(1))) void*)g,
                                   (__attribute__((address_space(3))) void*)l,
                                   16, 0, 0);
}

// ---------------------------------------------------------------------------
// 128x128-tile GEMM core, BK=64: C = A[M][K] * Bt[N][K]^T  (bf16, fp32 acc)
// 256 threads = 4 waves in 2x2; XOR bank swizzle on 16B k-groups
// (R1->R2 evidence: LDS conflicts 6.3M -> 0).
// ---------------------------------------------------------------------------
__device__ __forceinline__ void gemm_core(const short* __restrict__ A,
                                          const short* __restrict__ Bt,
                                          int lda, int ldb,
                                          int row0, int col0, int kIters,
                                          f32x4 acc[4][4],
                                          short* lA, short* lB) {
  const int tid  = threadIdx.x;
  const int wave = tid >> 6;
  const int lane = tid & 63;
  const int quad = lane >> 4;
  const int l16  = lane & 15;

  const f32x4 zero = {0.f, 0.f, 0.f, 0.f};
#pragma unroll
  for (int i = 0; i < 4; ++i)
#pragma unroll
    for (int j = 0; j < 4; ++j) acc[i][j] = zero;

  const int srow = tid >> 3;                    // 0..31
  const int gcol = ((tid & 7) ^ (srow & 7)) * 8;
  const short* A1 = A + (size_t)(row0 + srow) * lda + gcol;
  const short* A2 = A + (size_t)(row0 + srow + 32) * lda + gcol;
  const short* A3 = A + (size_t)(row0 + srow + 64) * lda + gcol;
  const short* A4 = A + (size_t)(row0 + srow + 96) * lda + gcol;
  const short* B1 = Bt + (size_t)(col0 + srow) * ldb + gcol;
  const short* B2 = Bt + (size_t)(col0 + srow + 32) * ldb + gcol;
  const short* B3 = Bt + (size_t)(col0 + srow + 64) * ldb + gcol;
  const short* B4 = Bt + (size_t)(col0 + srow + 96) * ldb + gcol;

  short* lA1 = lA + wave * 512;
  short* lA2 = lA + 2048 + wave * 512;
  short* lA3 = lA + 4096 + wave * 512;
  short* lA4 = lA + 6144 + wave * 512;
  short* lB1 = lB + wave * 512;
  short* lB2 = lB + 2048 + wave * 512;
  short* lB3 = lB + 4096 + wave * 512;
  short* lB4 = lB + 6144 + wave * 512;

  const int rswz  = l16 & 7;
  const int slot0 = (quad ^ rswz) * 8;
  const int slot1 = ((4 + quad) ^ rswz) * 8;
  const short* aRow = lA + ((wave >> 1) * 64 + l16) * 64;
  const short* bRow = lB + ((wave & 1) * 64 + l16) * 64;

  for (int it = 0; it < kIters; ++it) {
    const int k0 = it * 64;
    gll16(A1 + k0, lA1);
    gll16(A2 + k0, lA2);
    gll16(A3 + k0, lA3);
    gll16(A4 + k0, lA4);
    gll16(B1 + k0, lB1);
    gll16(B2 + k0, lB2);
    gll16(B3 + k0, lB3);
    gll16(B4 + k0, lB4);
    __syncthreads();

#pragma unroll
    for (int s = 0; s < 2; ++s) {
      const int so = s ? slot1 : slot0;
      short8 af[4], bfr[4];
#pragma unroll
      for (int i = 0; i < 4; ++i) af[i] = *(const short8*)(aRow + i * 1024 + so);
#pragma unroll
      for (int j = 0; j < 4; ++j) bfr[j] = *(const short8*)(bRow + j * 1024 + so);
#pragma unroll
      for (int i = 0; i < 4; ++i)
#pragma unroll
        for (int j = 0; j < 4; ++j)
          acc[i][j] = __builtin_amdgcn_mfma_f32_16x16x32_bf16(af[i], bfr[j], acc[i][j], 0, 0, 0);
    }
    __syncthreads();
  }
}

// C/D layout: row = quad*4 + reg, col = l16  (verified m89)
#define EPILOGUE_VARS                         \
  const int lane = threadIdx.x & 63;          \
  const int wave = threadIdx.x >> 6;          \
  const int quad = lane >> 4;                 \
  const int l16  = lane & 15;                 \
  const int rb   = (wave >> 1) * 64;          \
  const int cb   = (wave & 1) * 64;

// ---------------------------------------------------------------------------
// setup: blocks [0,8192) cast X->Xb; [8192,11264) transpose W->Wt;
//        [11264,11272) zero rowsum; [11272] zero cnt.
__global__ __launch_bounds__(256) void setup_kernel(const float* __restrict__ X,
                                                    const float* __restrict__ W,
                                                    short* __restrict__ Xb,
                                                    short* __restrict__ Wt,
                                                    float* __restrict__ rs,
                                                    int* __restrict__ cnt) {
  const int bid = blockIdx.x;
  if (bid < 8192) {
    const int i = (bid * 256 + threadIdx.x) * 4;
    const f32x4 v = *(const f32x4*)(X + i);
    s16x4 o;
    o.x = f2bf(v.x); o.y = f2bf(v.y); o.z = f2bf(v.z); o.w = f2bf(v.w);
    *(s16x4*)(Xb + i) = o;
  } else if (bid < 11264) {
    __shared__ float tile[32][33];
    const int r  = bid - 8192;
    const int ni = r % 96;
    const int ki = r / 96;
    const int tx = threadIdx.x & 31;
    const int ty = threadIdx.x >> 5;
#pragma unroll
    for (int rr = 0; rr < 4; ++rr)
      tile[ty + rr * 8][tx] = W[(size_t)(ki * 32 + ty + rr * 8) * 3072 + ni * 32 + tx];
    __syncthreads();
#pragma unroll
    for (int rr = 0; rr < 4; ++rr)
      Wt[(size_t)(ni * 32 + ty + rr * 8) * 1024 + ki * 32 + tx] = f2bf(tile[tx][ty + rr * 8]);
  } else if (bid < 11272) {
    const int i = (bid - 11264) * 1024 + threadIdx.x * 4;
    const f32x4 zero = {0.f, 0.f, 0.f, 0.f};
    *(f32x4*)(rs + i) = zero;
  } else {
    if (threadIdx.x < 64) cnt[threadIdx.x] = 0;
  }
}

// QKV: [8192x1024] x Wt[3072x1024]^T.  Q,K row-major [s][d]; V-columns
// written DIRECTLY transposed into Vt[b][d][s] via packed 8B stores.
__global__ __launch_bounds__(256) void qkv_gemm_kernel(const short* __restrict__ Xb,
                                                       const short* __restrict__ Wt,
                                                       short* __restrict__ Q,
                                                       short* __restrict__ K,
                                                       short* __restrict__ Vt) {
  __shared__ short lA[8192], lB[8192];
  const int br = blockIdx.x / 24;
  const int bc = blockIdx.x % 24;
  f32x4 acc[4][4];
  gemm_core(Xb, Wt, 1024, 1024, br * 128, bc * 128, 16, acc, lA, lB);

  EPILOGUE_VARS
  const int rbase = br * 128 + rb;
  const int cbase = bc * 128 + cb;
  if (bc < 16) {
#pragma unroll
    for (int i = 0; i < 4; ++i)
#pragma unroll
      for (int j = 0; j < 4; ++j) {
        const int col = cbase + j * 16 + l16;
        short* dst = (col < 1024) ? Q : K;
        const int n = col & 1023;
#pragma unroll
        for (int r = 0; r < 4; ++r) {
          const int row = rbase + i * 16 + quad * 4 + r;
          dst[(size_t)row * 1024 + n] = f2bf(acc[i][j][r]);
        }
      }
  } else {
    const int b  = rbase >> 11;
    const int s0 = rbase & 2047;
    short* VtB = Vt + (size_t)b * 1024 * 2048;
#pragma unroll
    for (int i = 0; i < 4; ++i) {
      const int sb = s0 + i * 16 + quad * 4;
#pragma unroll
      for (int j = 0; j < 4; ++j) {
        const int d = cbase - 2048 + j * 16 + l16;
        s16x4 pk;
        pk.x = f2bf(acc[i][j][0]);
        pk.y = f2bf(acc[i][j][1]);
        pk.z = f2bf(acc[i][j][2]);
        pk.w = f2bf(acc[i][j][3]);
        *(s16x4*)(VtB + (size_t)d * 2048 + sb) = pk;
      }
    }
  }
}

// Fused qk->pv with per-(b,qi) ready flags.  1056 blocks.
__global__ __launch_bounds__(256, 3) void attn_kernel(const short* __restrict__ Q,
                                                      const short* __restrict__ K,
                                                      const short* __restrict__ Vt,
                                                      short* __restrict__ E,
                                                      float* __restrict__ rs,
                                                      int* __restrict__ cnt,
                                                      float* __restrict__ out) {
  __shared__ short lA[8192], lB[8192];
  if (blockIdx.x < 544) {
    // ---- qk tile: heavy rows (qi=15) first, batches interleaved ----
    const int t = blockIdx.x >> 2;   // 0..135
    const int b = blockIdx.x & 3;
    int qi = 15, off = t;
    while (off >= qi + 1) { off -= qi + 1; qi--; }
    const int ki = off;

    f32x4 acc[4][4];
    const short* Qb = Q + (size_t)b * 2048 * 1024;
    const short* Kb = K + (size_t)b * 2048 * 1024;
    gemm_core(Qb, Kb, 1024, 1024, qi * 128, ki * 128, 16, acc, lA, lB);

    EPILOGUE_VARS
    short* Eb  = E + (size_t)b * 2048 * 2048;
    float* rsb = rs + b * 2048;
    const int rbase = qi * 128 + rb;
    const int cbase = ki * 128 + cb;
    const bool diag = (qi == ki);
#pragma unroll
    for (int i = 0; i < 4; ++i)
#pragma unroll
      for (int r = 0; r < 4; ++r) {
        const int row = rbase + i * 16 + quad * 4 + r;
        float partial = 0.f;
#pragma unroll
        for (int j = 0; j < 4; ++j) {
          const int col = cbase + j * 16 + l16;
          float e = __expf(acc[i][j][r] * 0.03125f);
          if (diag && col > row) e = 0.f;
          partial += e;
          Eb[(size_t)row * 2048 + col] = f2bf(e);
        }
        partial += __shfl_xor(partial, 1);
        partial += __shfl_xor(partial, 2);
        partial += __shfl_xor(partial, 4);
        partial += __shfl_xor(partial, 8);
        if (l16 == 0) atomicAdd(rsb + row, partial);
      }
    // publish: E tile + rowsum contributions visible before counter bump
    __threadfence();
    __syncthreads();
    if (threadIdx.x == 0)
      __hip_atomic_fetch_add(cnt + b * 16 + qi, 1,
                             __ATOMIC_RELEASE, __HIP_MEMORY_SCOPE_AGENT);
  } else {
    // ---- pv tile: wait for row-block qi complete, then (E x V)/rowsum ----
    const int r  = blockIdx.x - 544;  // 0..511
    const int t  = r >> 2;            // 0..127
    const int b  = r & 3;
    const int qi = 15 - (t >> 3);     // heavy rows first
    const int dj = t & 7;

    if (threadIdx.x == 0) {
      int guard = 0;
      while (__hip_atomic_load(cnt + b * 16 + qi,
                               __ATOMIC_ACQUIRE, __HIP_MEMORY_SCOPE_AGENT) < qi + 1) {
        __builtin_amdgcn_s_sleep(8);
        if (++guard > (1 << 22)) break;   // bounded: fail visibly, never hang
      }
    }
    __syncthreads();
    // acquire on every thread so subsequent loads see fresh data
    (void)__hip_atomic_load(cnt + b * 16 + qi,
                            __ATOMIC_ACQUIRE, __HIP_MEMORY_SCOPE_AGENT);

    f32x4 acc[4][4];
    const short* Eb  = E + (size_t)b * 2048 * 2048;
    const short* Vtb = Vt + (size_t)b * 1024 * 2048;
    gemm_core(Eb, Vtb, 2048, 2048, qi * 128, dj * 128, (qi + 1) * 2, acc, lA, lB);

    EPILOGUE_VARS
    float* ob = out + (size_t)b * 2048 * 1024;
    const float* rsb = rs + b * 2048;
    const int rbase = qi * 128 + rb;
    const int cbase = dj * 128 + cb;
#pragma unroll
    for (int i = 0; i < 4; ++i)
#pragma unroll
      for (int r2 = 0; r2 < 4; ++r2) {
        const int row = rbase + i * 16 + quad * 4 + r2;
        const float inv = 1.f / rsb[row];
#pragma unroll
        for (int j = 0; j < 4; ++j) {
          const int col = cbase + j * 16 + l16;
          ob[(size_t)row * 1024 + col] = acc[i][j][r2] * inv;
        }
      }
  }
}

// ---------------------------------------------------------------------------
extern "C" void kernel_launch(void* const* d_in, const int* in_sizes, int n_in,
                              void* d_out, int out_size, void* d_ws, size_t ws_size,
                              hipStream_t stream) {
  const float* X = (const float*)d_in[0];
  const float* W = (const float*)d_in[1];
  float* out = (float*)d_out;
  char* w = (char*)d_ws;

  short* Xb = (short*)(w + 0);
  short* Wt = (short*)(w + 16777216);
  short* E  = (short*)(w + 0);          // overlays Xb,Wt (dead after qkv)
  float* rs = (float*)(w + 50331648);
  int*  cnt = (int*)(w + 50364416);
  short* Q  = (short*)(w + 67108864);
  short* K  = (short*)(w + 83886080);
  short* Vt = (short*)(w + 100663296);

  hipLaunchKernelGGL(setup_kernel,    dim3(11273), dim3(256), 0, stream, X, W, Xb, Wt, rs, cnt);
  hipLaunchKernelGGL(qkv_gemm_kernel, dim3(1536),  dim3(256), 0, stream, Xb, Wt, Q, K, Vt);
  hipLaunchKernelGGL(attn_kernel,     dim3(1056),  dim3(256), 0, stream, Q, K, Vt, E, rs, cnt, out);
}

// Round 7
// 253.454 us; speedup vs baseline: 1.6084x; 1.6084x over previous
//
#include <hip/hip_runtime.h>
#include <hip/hip_bf16.h>

// B=4, S=2048, D=1024.  M = B*S = 8192.
// Workspace layout (bytes):
//   [0,         33554432)  : E bf16 (4*2048*2048) = exp(scores)
//     overlay (dead before qk runs):
//     [0,         16777216) : Xb  bf16 (8192*1024)
//     [16777216,  23068672) : Wt  bf16 (3072*1024)
//   [50331648,  50364416)  : rowsum fp32 (8192)   (zeroed by setup)
//   [67108864,  83886080)  : Q bf16 (8192*1024)
//   [83886080, 100663296)  : K bf16 (8192*1024)
//   [100663296,117440512)  : Vt bf16 (4*1024*2048) -- written DIRECTLY by qkv
//
// Pipeline (4 launches):
//   setup : cast X->bf16, transpose W->Wt bf16, zero rowsum
//   qkv   : 128x128/BK=64 core (structural plateau, 64 us, keep)
//   qk    : 64x128-tile 2-wave blocks, BK=32: E=exp(QK^T/32)+rowsums,
//           1088 blocks (4.25/CU) -- R6 analysis: these phases were
//           grid-limited to ~2 blocks/CU and latency-bound; smaller
//           blocks give ~4/CU and 2x the independent barriers.
//   pv    : same small-block core: out=(E x V)/rowsum, 1024 blocks.
//
// R6 post-mortem: spin-wait fusion regressed 2.5x (acquire-scope polls
// invalidate caches; spinning blocks burn residency).  Reverted.

typedef __attribute__((ext_vector_type(8))) short short8;
typedef __attribute__((ext_vector_type(4))) short s16x4;
typedef __attribute__((ext_vector_type(4))) float f32x4;

__device__ __forceinline__ short f2bf(float f) {
  __hip_bfloat16 h = __float2bfloat16(f);
  return *reinterpret_cast<short*>(&h);
}

__device__ __forceinline__ void gll16(const void* g, void* l) {
  __builtin_amdgcn_global_load_lds((const __attribute__((address_space(1))) void*)g,
                                   (__attribute__((address_space(3))) void*)l,
                                   16, 0, 0);
}

// ---------------------------------------------------------------------------
// 128x128-tile GEMM core, BK=64, 4 waves (qkv only).  XOR bank swizzle on
// 16B k-groups (R1->R2: LDS conflicts 6.3M -> 0).
// ---------------------------------------------------------------------------
__device__ __forceinline__ void gemm_core(const short* __restrict__ A,
                                          const short* __restrict__ Bt,
                                          int lda, int ldb,
                                          int row0, int col0, int kIters,
                                          f32x4 acc[4][4],
                                          short* lA, short* lB) {
  const int tid  = threadIdx.x;
  const int wave = tid >> 6;
  const int lane = tid & 63;
  const int quad = lane >> 4;
  const int l16  = lane & 15;

  const f32x4 zero = {0.f, 0.f, 0.f, 0.f};
#pragma unroll
  for (int i = 0; i < 4; ++i)
#pragma unroll
    for (int j = 0; j < 4; ++j) acc[i][j] = zero;

  const int srow = tid >> 3;                    // 0..31
  const int gcol = ((tid & 7) ^ (srow & 7)) * 8;
  const short* A1 = A + (size_t)(row0 + srow) * lda + gcol;
  const short* A2 = A + (size_t)(row0 + srow + 32) * lda + gcol;
  const short* A3 = A + (size_t)(row0 + srow + 64) * lda + gcol;
  const short* A4 = A + (size_t)(row0 + srow + 96) * lda + gcol;
  const short* B1 = Bt + (size_t)(col0 + srow) * ldb + gcol;
  const short* B2 = Bt + (size_t)(col0 + srow + 32) * ldb + gcol;
  const short* B3 = Bt + (size_t)(col0 + srow + 64) * ldb + gcol;
  const short* B4 = Bt + (size_t)(col0 + srow + 96) * ldb + gcol;

  short* lA1 = lA + wave * 512;
  short* lA2 = lA + 2048 + wave * 512;
  short* lA3 = lA + 4096 + wave * 512;
  short* lA4 = lA + 6144 + wave * 512;
  short* lB1 = lB + wave * 512;
  short* lB2 = lB + 2048 + wave * 512;
  short* lB3 = lB + 4096 + wave * 512;
  short* lB4 = lB + 6144 + wave * 512;

  const int rswz  = l16 & 7;
  const int slot0 = (quad ^ rswz) * 8;
  const int slot1 = ((4 + quad) ^ rswz) * 8;
  const short* aRow = lA + ((wave >> 1) * 64 + l16) * 64;
  const short* bRow = lB + ((wave & 1) * 64 + l16) * 64;

  for (int it = 0; it < kIters; ++it) {
    const int k0 = it * 64;
    gll16(A1 + k0, lA1);
    gll16(A2 + k0, lA2);
    gll16(A3 + k0, lA3);
    gll16(A4 + k0, lA4);
    gll16(B1 + k0, lB1);
    gll16(B2 + k0, lB2);
    gll16(B3 + k0, lB3);
    gll16(B4 + k0, lB4);
    __syncthreads();

#pragma unroll
    for (int s = 0; s < 2; ++s) {
      const int so = s ? slot1 : slot0;
      short8 af[4], bfr[4];
#pragma unroll
      for (int i = 0; i < 4; ++i) af[i] = *(const short8*)(aRow + i * 1024 + so);
#pragma unroll
      for (int j = 0; j < 4; ++j) bfr[j] = *(const short8*)(bRow + j * 1024 + so);
#pragma unroll
      for (int i = 0; i < 4; ++i)
#pragma unroll
        for (int j = 0; j < 4; ++j)
          acc[i][j] = __builtin_amdgcn_mfma_f32_16x16x32_bf16(af[i], bfr[j], acc[i][j], 0, 0, 0);
    }
    __syncthreads();
  }
}

// ---------------------------------------------------------------------------
// 64x128-tile GEMM core, BK=32, 2 waves (128 threads).  Wave w owns cols
// [w*64, w*64+64).  LDS: A 64x32 (4KB) + B 128x32 (8KB) = 12KB -> many
// blocks/CU.  Same XOR swizzle family: row r stores k-group kg (of 4) at
// slot kg ^ ((r>>1)&3), applied on the global source address.
// ---------------------------------------------------------------------------
__device__ __forceinline__ void gemm_core64(const short* __restrict__ A,
                                            const short* __restrict__ Bt,
                                            int lda, int ldb,
                                            int row0, int col0, int kIters,
                                            f32x4 acc[4][4],
                                            short* lA, short* lB) {
  const int tid  = threadIdx.x;      // 0..127
  const int wave = tid >> 6;         // 0..1
  const int lane = tid & 63;
  const int quad = lane >> 4;
  const int l16  = lane & 15;

  const f32x4 zero = {0.f, 0.f, 0.f, 0.f};
#pragma unroll
  for (int i = 0; i < 4; ++i)
#pragma unroll
    for (int j = 0; j < 4; ++j) acc[i][j] = zero;

  // staging: 16B chunks; A: 256 chunks (rows 0..63), B: 512 (rows 0..127).
  // thread t: A chunks t, t+128; B chunks t, t+128, t+256, t+384.
  // chunk c -> row c>>2, slot c&3; (row+32k)>>1&3 invariant -> one XOR.
  const int srow = tid >> 2;                         // 0..31
  const int gcol = ((tid & 3) ^ ((srow >> 1) & 3)) * 8;
  const short* A1 = A + (size_t)(row0 + srow) * lda + gcol;
  const short* A2 = A + (size_t)(row0 + srow + 32) * lda + gcol;
  const short* B1 = Bt + (size_t)(col0 + srow) * ldb + gcol;
  const short* B2 = Bt + (size_t)(col0 + srow + 32) * ldb + gcol;
  const short* B3 = Bt + (size_t)(col0 + srow + 64) * ldb + gcol;
  const short* B4 = Bt + (size_t)(col0 + srow + 96) * ldb + gcol;

  short* lA1 = lA + wave * 512;          // wave-uniform bases, lane stride 16B
  short* lA2 = lA + 1024 + wave * 512;
  short* lB1 = lB + wave * 512;
  short* lB2 = lB + 1024 + wave * 512;
  short* lB3 = lB + 2048 + wave * 512;
  short* lB4 = lB + 3072 + wave * 512;

  // fragment reads: A row = i*16+l16, B row = wave*64 + j*16 + l16;
  // (row>>1)&3 == (l16>>1)&3 for all i/j (i*8, j*8 are 0 mod 4... i*16>>1=i*8,
  // i*8 mod 4 == 0) -> one slot formula.
  const int slot = ((quad ^ ((l16 >> 1) & 3))) * 8;
  const short* aBase = lA + l16 * 32 + slot;
  const short* bBase = lB + wave * 2048 + l16 * 32 + slot;

  for (int it = 0; it < kIters; ++it) {
    const int k0 = it * 32;
    gll16(A1 + k0, lA1);
    gll16(A2 + k0, lA2);
    gll16(B1 + k0, lB1);
    gll16(B2 + k0, lB2);
    gll16(B3 + k0, lB3);
    gll16(B4 + k0, lB4);
    __syncthreads();

    short8 af[4], bfr[4];
#pragma unroll
    for (int i = 0; i < 4; ++i) af[i] = *(const short8*)(aBase + i * 512);
#pragma unroll
    for (int j = 0; j < 4; ++j) bfr[j] = *(const short8*)(bBase + j * 512);
#pragma unroll
    for (int i = 0; i < 4; ++i)
#pragma unroll
      for (int j = 0; j < 4; ++j)
        acc[i][j] = __builtin_amdgcn_mfma_f32_16x16x32_bf16(af[i], bfr[j], acc[i][j], 0, 0, 0);
    __syncthreads();
  }
}

// C/D layout: row = quad*4 + reg, col = l16  (verified m89)
#define EPILOGUE_VARS                         \
  const int lane = threadIdx.x & 63;          \
  const int wave = threadIdx.x >> 6;          \
  const int quad = lane >> 4;                 \
  const int l16  = lane & 15;                 \
  const int rb   = (wave >> 1) * 64;          \
  const int cb   = (wave & 1) * 64;

// ---------------------------------------------------------------------------
// setup: blocks [0,8192) cast X->Xb; [8192,11264) transpose W->Wt;
//        [11264,11272) zero rowsum.
__global__ __launch_bounds__(256) void setup_kernel(const float* __restrict__ X,
                                                    const float* __restrict__ W,
                                                    short* __restrict__ Xb,
                                                    short* __restrict__ Wt,
                                                    float* __restrict__ rs) {
  const int bid = blockIdx.x;
  if (bid < 8192) {
    const int i = (bid * 256 + threadIdx.x) * 4;
    const f32x4 v = *(const f32x4*)(X + i);
    s16x4 o;
    o.x = f2bf(v.x); o.y = f2bf(v.y); o.z = f2bf(v.z); o.w = f2bf(v.w);
    *(s16x4*)(Xb + i) = o;
  } else if (bid < 11264) {
    __shared__ float tile[32][33];
    const int r  = bid - 8192;
    const int ni = r % 96;
    const int ki = r / 96;
    const int tx = threadIdx.x & 31;
    const int ty = threadIdx.x >> 5;
#pragma unroll
    for (int rr = 0; rr < 4; ++rr)
      tile[ty + rr * 8][tx] = W[(size_t)(ki * 32 + ty + rr * 8) * 3072 + ni * 32 + tx];
    __syncthreads();
#pragma unroll
    for (int rr = 0; rr < 4; ++rr)
      Wt[(size_t)(ni * 32 + ty + rr * 8) * 1024 + ki * 32 + tx] = f2bf(tile[tx][ty + rr * 8]);
  } else {
    const int i = (bid - 11264) * 1024 + threadIdx.x * 4;
    const f32x4 zero = {0.f, 0.f, 0.f, 0.f};
    *(f32x4*)(rs + i) = zero;
  }
}

// QKV: [8192x1024] x Wt[3072x1024]^T.  Q,K row-major [s][d]; V-columns
// written DIRECTLY transposed into Vt[b][d][s] via packed 8B stores.
__global__ __launch_bounds__(256) void qkv_gemm_kernel(const short* __restrict__ Xb,
                                                       const short* __restrict__ Wt,
                                                       short* __restrict__ Q,
                                                       short* __restrict__ K,
                                                       short* __restrict__ Vt) {
  __shared__ short lA[8192], lB[8192];
  const int br = blockIdx.x / 24;
  const int bc = blockIdx.x % 24;
  f32x4 acc[4][4];
  gemm_core(Xb, Wt, 1024, 1024, br * 128, bc * 128, 16, acc, lA, lB);

  EPILOGUE_VARS
  const int rbase = br * 128 + rb;
  const int cbase = bc * 128 + cb;
  if (bc < 16) {
#pragma unroll
    for (int i = 0; i < 4; ++i)
#pragma unroll
      for (int j = 0; j < 4; ++j) {
        const int col = cbase + j * 16 + l16;
        short* dst = (col < 1024) ? Q : K;
        const int n = col & 1023;
#pragma unroll
        for (int r = 0; r < 4; ++r) {
          const int row = rbase + i * 16 + quad * 4 + r;
          dst[(size_t)row * 1024 + n] = f2bf(acc[i][j][r]);
        }
      }
  } else {
    const int b  = rbase >> 11;
    const int s0 = rbase & 2047;
    short* VtB = Vt + (size_t)b * 1024 * 2048;
#pragma unroll
    for (int i = 0; i < 4; ++i) {
      const int sb = s0 + i * 16 + quad * 4;
#pragma unroll
      for (int j = 0; j < 4; ++j) {
        const int d = cbase - 2048 + j * 16 + l16;
        s16x4 pk;
        pk.x = f2bf(acc[i][j][0]);
        pk.y = f2bf(acc[i][j][1]);
        pk.z = f2bf(acc[i][j][2]);
        pk.w = f2bf(acc[i][j][3]);
        *(s16x4*)(VtB + (size_t)d * 2048 + sb) = pk;
      }
    }
  }
}

// qk: 64-row x 128-col tiles, E = exp(QK^T/32) + rowsum atomics.
// Row-tile qi (64 rows) needs k-tiles 0..qi>>1; diagonal k-tile masks
// col>row (writes the zero padding pv reads).  272 tiles/batch x 4 = 1088.
__global__ __launch_bounds__(128) void qk_kernel(const short* __restrict__ Q,
                                                 const short* __restrict__ K,
                                                 short* __restrict__ E,
                                                 float* __restrict__ rs) {
  __shared__ short lA[2048], lB[4096];
  const int t = blockIdx.x >> 2;   // 0..271
  const int b = blockIdx.x & 3;
  int qi = 31, off = t;            // heavy rows first
  while (off >= (qi >> 1) + 1) { off -= (qi >> 1) + 1; qi--; }
  const int ki = off;

  f32x4 acc[4][4];
  const short* Qb = Q + (size_t)b * 2048 * 1024;
  const short* Kb = K + (size_t)b * 2048 * 1024;
  gemm_core64(Qb, Kb, 1024, 1024, qi * 64, ki * 128, 32, acc, lA, lB);

  const int lane = threadIdx.x & 63;
  const int wave = threadIdx.x >> 6;
  const int quad = lane >> 4;
  const int l16  = lane & 15;
  short* Eb  = E + (size_t)b * 2048 * 2048;
  float* rsb = rs + b * 2048;
  const int rbase = qi * 64;
  const int cbase = ki * 128 + wave * 64;
  const bool diag = (ki == (qi >> 1));
#pragma unroll
  for (int i = 0; i < 4; ++i)
#pragma unroll
    for (int r = 0; r < 4; ++r) {
      const int row = rbase + i * 16 + quad * 4 + r;
      float partial = 0.f;
#pragma unroll
      for (int j = 0; j < 4; ++j) {
        const int col = cbase + j * 16 + l16;
        float e = __expf(acc[i][j][r] * 0.03125f);
        if (diag && col > row) e = 0.f;
        partial += e;
        Eb[(size_t)row * 2048 + col] = f2bf(e);
      }
      partial += __shfl_xor(partial, 1);
      partial += __shfl_xor(partial, 2);
      partial += __shfl_xor(partial, 4);
      partial += __shfl_xor(partial, 8);
      if (l16 == 0) atomicAdd(rsb + row, partial);
    }
}

// pv: 64-row x 128-col out tiles, out = (E x V)/rowsum.  K-extent per
// row-tile qi is ((qi>>1)+1)*128 (causal).  32 qi x 8 dj x 4 b = 1024 blocks,
// heavy rows first.
__global__ __launch_bounds__(128) void pv_kernel(const short* __restrict__ E,
                                                 const short* __restrict__ Vt,
                                                 const float* __restrict__ rs,
                                                 float* __restrict__ out) {
  __shared__ short lA[2048], lB[4096];
  const int t  = blockIdx.x >> 2;   // 0..255
  const int b  = blockIdx.x & 3;
  const int qi = 31 - (t >> 3);
  const int dj = t & 7;

  f32x4 acc[4][4];
  const short* Eb  = E + (size_t)b * 2048 * 2048;
  const short* Vtb = Vt + (size_t)b * 1024 * 2048;
  gemm_core64(Eb, Vtb, 2048, 2048, qi * 64, dj * 128, ((qi >> 1) + 1) * 4, acc, lA, lB);

  const int lane = threadIdx.x & 63;
  const int wave = threadIdx.x >> 6;
  const int quad = lane >> 4;
  const int l16  = lane & 15;
  float* ob = out + (size_t)b * 2048 * 1024;
  const float* rsb = rs + b * 2048;
  const int rbase = qi * 64;
  const int cbase = dj * 128 + wave * 64;
#pragma unroll
  for (int i = 0; i < 4; ++i)
#pragma unroll
    for (int r2 = 0; r2 < 4; ++r2) {
      const int row = rbase + i * 16 + quad * 4 + r2;
      const float inv = 1.f / rsb[row];
#pragma unroll
      for (int j = 0; j < 4; ++j) {
        const int col = cbase + j * 16 + l16;
        ob[(size_t)row * 1024 + col] = acc[i][j][r2] * inv;
      }
    }
}

// ---------------------------------------------------------------------------
extern "C" void kernel_launch(void* const* d_in, const int* in_sizes, int n_in,
                              void* d_out, int out_size, void* d_ws, size_t ws_size,
                              hipStream_t stream) {
  const float* X = (const float*)d_in[0];
  const float* W = (const float*)d_in[1];
  float* out = (float*)d_out;
  char* w = (char*)d_ws;

  short* Xb = (short*)(w + 0);
  short* Wt = (short*)(w + 16777216);
  short* E  = (short*)(w + 0);          // overlays Xb,Wt (dead after qkv)
  float* rs = (float*)(w + 50331648);
  short* Q  = (short*)(w + 67108864);
  short* K  = (short*)(w + 83886080);
  short* Vt = (short*)(w + 100663296);

  hipLaunchKernelGGL(setup_kernel,    dim3(11272), dim3(256), 0, stream, X, W, Xb, Wt, rs);
  hipLaunchKernelGGL(qkv_gemm_kernel, dim3(1536),  dim3(256), 0, stream, Xb, Wt, Q, K, Vt);
  hipLaunchKernelGGL(qk_kernel,       dim3(1088),  dim3(128), 0, stream, Q, K, E, rs);
  hipLaunchKernelGGL(pv_kernel,       dim3(1024),  dim3(128), 0, stream, E, Vt, rs, out);
}

// Round 8
// 247.892 us; speedup vs baseline: 1.6445x; 1.0224x over previous
//
#include <hip/hip_runtime.h>
#include <hip/hip_bf16.h>

// B=4, S=2048, D=1024.  M = B*S = 8192.
// Workspace layout (bytes):
//   [0,         33554432)  : E bf16 (4*2048*2048) = exp(scores)
//     overlay (dead before qk runs):
//     [0,         16777216) : Xb  bf16 (8192*1024)
//     [16777216,  23068672) : Wt  bf16 (3072*1024)
//   [50331648,  50364416)  : rowsum fp32 (8192)   (zeroed by setup)
//   [67108864,  83886080)  : Q bf16 (8192*1024)
//   [83886080, 100663296)  : K bf16 (8192*1024)
//   [100663296,117440512)  : Vt bf16 (4*1024*2048) -- written DIRECTLY by qkv
//
// Pipeline (5 launches):
//   setup  : cast X->bf16, transpose W->Wt bf16, zero rowsum
//   qkv x2 : split into two 768-block dispatches (~33us each) so that any
//            other dispatch >33us becomes visible in rocprof top-5 (R7: all
//            five slots were 66us qkv replays -- phase durations invisible).
//   qk     : SINGLE-WAVE blocks (64 thr), 64x64 tiles, BK=32:
//            E=exp(QK^T/32)+rowsums.  2112 blocks (~8/CU).  R7 theory:
//            latency-bound phases want independent per-wave pipelines;
//            1-wave blocks need no s_barrier (waitcnt only) and give ~8
//            uncoupled streams/CU vs 4.25 coupled pairs.
//   pv     : same 1-wave core: out=(E x V)/rowsum, 2048 blocks, heavy first.

typedef __attribute__((ext_vector_type(8))) short short8;
typedef __attribute__((ext_vector_type(4))) short s16x4;
typedef __attribute__((ext_vector_type(4))) float f32x4;

__device__ __forceinline__ short f2bf(float f) {
  __hip_bfloat16 h = __float2bfloat16(f);
  return *reinterpret_cast<short*>(&h);
}

__device__ __forceinline__ void gll16(const void* g, void* l) {
  __builtin_amdgcn_global_load_lds((const __attribute__((address_space(1))) void*)g,
                                   (__attribute__((address_space(3))) void*)l,
                                   16, 0, 0);
}

// ---------------------------------------------------------------------------
// 128x128-tile GEMM core, BK=64, 4 waves (qkv only).  XOR bank swizzle on
// 16B k-groups (R1->R2: LDS conflicts 6.3M -> 0).
// ---------------------------------------------------------------------------
__device__ __forceinline__ void gemm_core(const short* __restrict__ A,
                                          const short* __restrict__ Bt,
                                          int lda, int ldb,
                                          int row0, int col0, int kIters,
                                          f32x4 acc[4][4],
                                          short* lA, short* lB) {
  const int tid  = threadIdx.x;
  const int wave = tid >> 6;
  const int lane = tid & 63;
  const int quad = lane >> 4;
  const int l16  = lane & 15;

  const f32x4 zero = {0.f, 0.f, 0.f, 0.f};
#pragma unroll
  for (int i = 0; i < 4; ++i)
#pragma unroll
    for (int j = 0; j < 4; ++j) acc[i][j] = zero;

  const int srow = tid >> 3;                    // 0..31
  const int gcol = ((tid & 7) ^ (srow & 7)) * 8;
  const short* A1 = A + (size_t)(row0 + srow) * lda + gcol;
  const short* A2 = A + (size_t)(row0 + srow + 32) * lda + gcol;
  const short* A3 = A + (size_t)(row0 + srow + 64) * lda + gcol;
  const short* A4 = A + (size_t)(row0 + srow + 96) * lda + gcol;
  const short* B1 = Bt + (size_t)(col0 + srow) * ldb + gcol;
  const short* B2 = Bt + (size_t)(col0 + srow + 32) * ldb + gcol;
  const short* B3 = Bt + (size_t)(col0 + srow + 64) * ldb + gcol;
  const short* B4 = Bt + (size_t)(col0 + srow + 96) * ldb + gcol;

  short* lA1 = lA + wave * 512;
  short* lA2 = lA + 2048 + wave * 512;
  short* lA3 = lA + 4096 + wave * 512;
  short* lA4 = lA + 6144 + wave * 512;
  short* lB1 = lB + wave * 512;
  short* lB2 = lB + 2048 + wave * 512;
  short* lB3 = lB + 4096 + wave * 512;
  short* lB4 = lB + 6144 + wave * 512;

  const int rswz  = l16 & 7;
  const int slot0 = (quad ^ rswz) * 8;
  const int slot1 = ((4 + quad) ^ rswz) * 8;
  const short* aRow = lA + ((wave >> 1) * 64 + l16) * 64;
  const short* bRow = lB + ((wave & 1) * 64 + l16) * 64;

  for (int it = 0; it < kIters; ++it) {
    const int k0 = it * 64;
    gll16(A1 + k0, lA1);
    gll16(A2 + k0, lA2);
    gll16(A3 + k0, lA3);
    gll16(A4 + k0, lA4);
    gll16(B1 + k0, lB1);
    gll16(B2 + k0, lB2);
    gll16(B3 + k0, lB3);
    gll16(B4 + k0, lB4);
    __syncthreads();

#pragma unroll
    for (int s = 0; s < 2; ++s) {
      const int so = s ? slot1 : slot0;
      short8 af[4], bfr[4];
#pragma unroll
      for (int i = 0; i < 4; ++i) af[i] = *(const short8*)(aRow + i * 1024 + so);
#pragma unroll
      for (int j = 0; j < 4; ++j) bfr[j] = *(const short8*)(bRow + j * 1024 + so);
#pragma unroll
      for (int i = 0; i < 4; ++i)
#pragma unroll
        for (int j = 0; j < 4; ++j)
          acc[i][j] = __builtin_amdgcn_mfma_f32_16x16x32_bf16(af[i], bfr[j], acc[i][j], 0, 0, 0);
    }
    __syncthreads();
  }
}

// ---------------------------------------------------------------------------
// 64x64-tile GEMM core, BK=32, ONE wave (64 threads).  LDS: A 64x32 (4KB) +
// B 64x32 (4KB).  __syncthreads in a 1-wave block is waitcnt-only (no
// s_barrier) -> fully independent per-wave pipeline.  Same XOR swizzle:
// row r stores 16B k-group kg at slot kg ^ ((r>>1)&3), applied on the
// global source address; fragment reads undo it.
// ---------------------------------------------------------------------------
__device__ __forceinline__ void gemm_core32(const short* __restrict__ A,
                                            const short* __restrict__ Bt,
                                            int lda, int ldb,
                                            int row0, int col0, int kIters,
                                            f32x4 acc[4][4],
                                            short* lA, short* lB) {
  const int lane = threadIdx.x;      // 0..63
  const int quad = lane >> 4;
  const int l16  = lane & 15;

  const f32x4 zero = {0.f, 0.f, 0.f, 0.f};
#pragma unroll
  for (int i = 0; i < 4; ++i)
#pragma unroll
    for (int j = 0; j < 4; ++j) acc[i][j] = zero;

  // staging: set q (q=0..3) covers rows 16q..16q+15; lane l -> row 16q+(l>>2),
  // slot l&3; LDS dest = base(q*1024B) + lane*16B.  ((row+16q)>>1)&3 is
  // q-invariant -> one XOR for all sets.
  const int srow = lane >> 2;                        // 0..15
  const int gcol = ((lane & 3) ^ ((srow >> 1) & 3)) * 8;
  const short* A1 = A + (size_t)(row0 + srow) * lda + gcol;
  const short* A2 = A + (size_t)(row0 + srow + 16) * lda + gcol;
  const short* A3 = A + (size_t)(row0 + srow + 32) * lda + gcol;
  const short* A4 = A + (size_t)(row0 + srow + 48) * lda + gcol;
  const short* B1 = Bt + (size_t)(col0 + srow) * ldb + gcol;
  const short* B2 = Bt + (size_t)(col0 + srow + 16) * ldb + gcol;
  const short* B3 = Bt + (size_t)(col0 + srow + 32) * ldb + gcol;
  const short* B4 = Bt + (size_t)(col0 + srow + 48) * ldb + gcol;

  // fragment reads: row m = i*16+l16; ((m)>>1)&3 == (l16>>1)&3 for all i.
  const int slot = (quad ^ ((l16 >> 1) & 3)) * 8;
  const short* aBase = lA + l16 * 32 + slot;
  const short* bBase = lB + l16 * 32 + slot;

  for (int it = 0; it < kIters; ++it) {
    const int k0 = it * 32;
    gll16(A1 + k0, lA);
    gll16(A2 + k0, lA + 512);
    gll16(A3 + k0, lA + 1024);
    gll16(A4 + k0, lA + 1536);
    gll16(B1 + k0, lB);
    gll16(B2 + k0, lB + 512);
    gll16(B3 + k0, lB + 1024);
    gll16(B4 + k0, lB + 1536);
    __syncthreads();   // 1-wave block: compiles to s_waitcnt only

    short8 af[4], bfr[4];
#pragma unroll
    for (int i = 0; i < 4; ++i) af[i] = *(const short8*)(aBase + i * 512);
#pragma unroll
    for (int j = 0; j < 4; ++j) bfr[j] = *(const short8*)(bBase + j * 512);
#pragma unroll
    for (int i = 0; i < 4; ++i)
#pragma unroll
      for (int j = 0; j < 4; ++j)
        acc[i][j] = __builtin_amdgcn_mfma_f32_16x16x32_bf16(af[i], bfr[j], acc[i][j], 0, 0, 0);
    __syncthreads();
  }
}

// C/D layout: row = quad*4 + reg, col = l16  (verified m89)
#define EPILOGUE_VARS                         \
  const int lane = threadIdx.x & 63;          \
  const int wave = threadIdx.x >> 6;          \
  const int quad = lane >> 4;                 \
  const int l16  = lane & 15;                 \
  const int rb   = (wave >> 1) * 64;          \
  const int cb   = (wave & 1) * 64;

// ---------------------------------------------------------------------------
// setup: blocks [0,8192) cast X->Xb; [8192,11264) transpose W->Wt;
//        [11264,11272) zero rowsum.
__global__ __launch_bounds__(256) void setup_kernel(const float* __restrict__ X,
                                                    const float* __restrict__ W,
                                                    short* __restrict__ Xb,
                                                    short* __restrict__ Wt,
                                                    float* __restrict__ rs) {
  const int bid = blockIdx.x;
  if (bid < 8192) {
    const int i = (bid * 256 + threadIdx.x) * 4;
    const f32x4 v = *(const f32x4*)(X + i);
    s16x4 o;
    o.x = f2bf(v.x); o.y = f2bf(v.y); o.z = f2bf(v.z); o.w = f2bf(v.w);
    *(s16x4*)(Xb + i) = o;
  } else if (bid < 11264) {
    __shared__ float tile[32][33];
    const int r  = bid - 8192;
    const int ni = r % 96;
    const int ki = r / 96;
    const int tx = threadIdx.x & 31;
    const int ty = threadIdx.x >> 5;
#pragma unroll
    for (int rr = 0; rr < 4; ++rr)
      tile[ty + rr * 8][tx] = W[(size_t)(ki * 32 + ty + rr * 8) * 3072 + ni * 32 + tx];
    __syncthreads();
#pragma unroll
    for (int rr = 0; rr < 4; ++rr)
      Wt[(size_t)(ni * 32 + ty + rr * 8) * 1024 + ki * 32 + tx] = f2bf(tile[tx][ty + rr * 8]);
  } else {
    const int i = (bid - 11264) * 1024 + threadIdx.x * 4;
    const f32x4 zero = {0.f, 0.f, 0.f, 0.f};
    *(f32x4*)(rs + i) = zero;
  }
}

// QKV: [8192x1024] x Wt[3072x1024]^T.  Q,K row-major [s][d]; V-columns
// written DIRECTLY transposed into Vt[b][d][s] via packed 8B stores.
// br0 selects the half-grid (row tiles br0..br0+31) -- split for profiling
// visibility.
__global__ __launch_bounds__(256) void qkv_gemm_kernel(const short* __restrict__ Xb,
                                                       const short* __restrict__ Wt,
                                                       short* __restrict__ Q,
                                                       short* __restrict__ K,
                                                       short* __restrict__ Vt,
                                                       int br0) {
  __shared__ short lA[8192], lB[8192];
  const int br = br0 + blockIdx.x / 24;
  const int bc = blockIdx.x % 24;
  f32x4 acc[4][4];
  gemm_core(Xb, Wt, 1024, 1024, br * 128, bc * 128, 16, acc, lA, lB);

  EPILOGUE_VARS
  const int rbase = br * 128 + rb;
  const int cbase = bc * 128 + cb;
  if (bc < 16) {
#pragma unroll
    for (int i = 0; i < 4; ++i)
#pragma unroll
      for (int j = 0; j < 4; ++j) {
        const int col = cbase + j * 16 + l16;
        short* dst = (col < 1024) ? Q : K;
        const int n = col & 1023;
#pragma unroll
        for (int r = 0; r < 4; ++r) {
          const int row = rbase + i * 16 + quad * 4 + r;
          dst[(size_t)row * 1024 + n] = f2bf(acc[i][j][r]);
        }
      }
  } else {
    const int b  = rbase >> 11;
    const int s0 = rbase & 2047;
    short* VtB = Vt + (size_t)b * 1024 * 2048;
#pragma unroll
    for (int i = 0; i < 4; ++i) {
      const int sb = s0 + i * 16 + quad * 4;
#pragma unroll
      for (int j = 0; j < 4; ++j) {
        const int d = cbase - 2048 + j * 16 + l16;
        s16x4 pk;
        pk.x = f2bf(acc[i][j][0]);
        pk.y = f2bf(acc[i][j][1]);
        pk.z = f2bf(acc[i][j][2]);
        pk.w = f2bf(acc[i][j][3]);
        *(s16x4*)(VtB + (size_t)d * 2048 + sb) = pk;
      }
    }
  }
}

// qk: 64x64 tiles, 1-wave blocks.  E = exp(QK^T/32) + rowsum atomics.
// Row-tile qi needs k-tiles 0..qi; diagonal tile (ki==qi) masks col>row
// (writes the zero padding pv reads).  528 tiles/batch x 4 = 2112 blocks,
// heavy rows (qi=31) first.
__global__ __launch_bounds__(64) void qk_kernel(const short* __restrict__ Q,
                                                const short* __restrict__ K,
                                                short* __restrict__ E,
                                                float* __restrict__ rs) {
  __shared__ short lA[2048], lB[2048];
  const int t = blockIdx.x >> 2;   // 0..527
  const int b = blockIdx.x & 3;
  int qi = 31, off = t;
  while (off >= qi + 1) { off -= qi + 1; qi--; }
  const int ki = off;

  f32x4 acc[4][4];
  const short* Qb = Q + (size_t)b * 2048 * 1024;
  const short* Kb = K + (size_t)b * 2048 * 1024;
  gemm_core32(Qb, Kb, 1024, 1024, qi * 64, ki * 64, 32, acc, lA, lB);

  const int lane = threadIdx.x;
  const int quad = lane >> 4;
  const int l16  = lane & 15;
  short* Eb  = E + (size_t)b * 2048 * 2048;
  float* rsb = rs + b * 2048;
  const int rbase = qi * 64;
  const int cbase = ki * 64;
  const bool diag = (ki == qi);
#pragma unroll
  for (int i = 0; i < 4; ++i)
#pragma unroll
    for (int r = 0; r < 4; ++r) {
      const int row = rbase + i * 16 + quad * 4 + r;
      float partial = 0.f;
#pragma unroll
      for (int j = 0; j < 4; ++j) {
        const int col = cbase + j * 16 + l16;
        float e = __expf(acc[i][j][r] * 0.03125f);
        if (diag && col > row) e = 0.f;
        partial += e;
        Eb[(size_t)row * 2048 + col] = f2bf(e);
      }
      partial += __shfl_xor(partial, 1);
      partial += __shfl_xor(partial, 2);
      partial += __shfl_xor(partial, 4);
      partial += __shfl_xor(partial, 8);
      if (l16 == 0) atomicAdd(rsb + row, partial);
    }
}

// pv: 64x64 out tiles, 1-wave blocks.  out = (E x V)/rowsum.  K-extent per
// row-tile qi is (qi+1)*64 (causal).  32 qi x 16 dj x 4 b = 2048 blocks,
// heavy rows first.
__global__ __launch_bounds__(64) void pv_kernel(const short* __restrict__ E,
                                                const short* __restrict__ Vt,
                                                const float* __restrict__ rs,
                                                float* __restrict__ out) {
  __shared__ short lA[2048], lB[2048];
  const int t  = blockIdx.x >> 2;   // 0..511
  const int b  = blockIdx.x & 3;
  const int qi = 31 - (t >> 4);
  const int dj = t & 15;

  f32x4 acc[4][4];
  const short* Eb  = E + (size_t)b * 2048 * 2048;
  const short* Vtb = Vt + (size_t)b * 1024 * 2048;
  gemm_core32(Eb, Vtb, 2048, 2048, qi * 64, dj * 64, (qi + 1) * 2, acc, lA, lB);

  const int lane = threadIdx.x;
  const int quad = lane >> 4;
  const int l16  = lane & 15;
  float* ob = out + (size_t)b * 2048 * 1024;
  const float* rsb = rs + b * 2048;
  const int rbase = qi * 64;
  const int cbase = dj * 64;
#pragma unroll
  for (int i = 0; i < 4; ++i)
#pragma unroll
    for (int r2 = 0; r2 < 4; ++r2) {
      const int row = rbase + i * 16 + quad * 4 + r2;
      const float inv = 1.f / rsb[row];
#pragma unroll
      for (int j = 0; j < 4; ++j) {
        const int col = cbase + j * 16 + l16;
        ob[(size_t)row * 1024 + col] = acc[i][j][r2] * inv;
      }
    }
}

// ---------------------------------------------------------------------------
extern "C" void kernel_launch(void* const* d_in, const int* in_sizes, int n_in,
                              void* d_out, int out_size, void* d_ws, size_t ws_size,
                              hipStream_t stream) {
  const float* X = (const float*)d_in[0];
  const float* W = (const float*)d_in[1];
  float* out = (float*)d_out;
  char* w = (char*)d_ws;

  short* Xb = (short*)(w + 0);
  short* Wt = (short*)(w + 16777216);
  short* E  = (short*)(w + 0);          // overlays Xb,Wt (dead after qkv)
  float* rs = (float*)(w + 50331648);
  short* Q  = (short*)(w + 67108864);
  short* K  = (short*)(w + 83886080);
  short* Vt = (short*)(w + 100663296);

  hipLaunchKernelGGL(setup_kernel,    dim3(11272), dim3(256), 0, stream, X, W, Xb, Wt, rs);
  hipLaunchKernelGGL(qkv_gemm_kernel, dim3(768),   dim3(256), 0, stream, Xb, Wt, Q, K, Vt, 0);
  hipLaunchKernelGGL(qkv_gemm_kernel, dim3(768),   dim3(256), 0, stream, Xb, Wt, Q, K, Vt, 32);
  hipLaunchKernelGGL(qk_kernel,       dim3(2112),  dim3(64),  0, stream, Q, K, E, rs);
  hipLaunchKernelGGL(pv_kernel,       dim3(2048),  dim3(64),  0, stream, E, Vt, rs, out);
}